// Round 23
// baseline (79.643 us; speedup 1.0000x reference)
//
#include <hip/hip_runtime.h>
#include <stdint.h>
#include <stddef.h>

typedef __bf16 bf16x8 __attribute__((ext_vector_type(8)));
typedef __bf16 bf16x4 __attribute__((ext_vector_type(4)));
typedef float  f32x4  __attribute__((ext_vector_type(4)));

#define MFMA16(A, B, C) __builtin_amdgcn_mfma_f32_16x16x32_bf16((A), (B), (C), 0, 0, 0)

// 0.125 (1/sqrt(64)) * log2(e), folded into Q at projection time.
#define QSCALE 0.18033688011112042f

// Raw v_exp_f32 (2^x); args bounded here so no range guards needed.
#if __has_builtin(__builtin_amdgcn_exp2f)
__device__ __forceinline__ float fast_exp2(float x) {
    return __builtin_amdgcn_exp2f(x);
}
#else
__device__ __forceinline__ float fast_exp2(float x) {
    float r;
    asm("v_exp_f32 %0, %1" : "=v"(r) : "v"(x));
    return r;
}
#endif

// Async global->LDS, 16B per lane. LDS dest is wave-uniform base + lane*16.
__device__ __forceinline__ void async_copy16(__bf16* lds, const __bf16* g) {
    __builtin_amdgcn_global_load_lds(
        (const __attribute__((address_space(1))) void*)g,
        (__attribute__((address_space(3))) void*)lds,
        16, 0, 0);
}

// ---------------------------------------------------------------------------
// Kernel 1: fused QKV projection (r19-verbatim).
//   x [32768][768] fp32 -> Q (pre-scaled by QSCALE), K bf16 row-major
//   [32768][64]; V stored CHUNK-MAJOR: Vc[b][128 chunks][64 h][32 k'] with
//   sigma key-permutation and the LDS stage swizzle baked in (attention V
//   DMA is fully linear: 1024 contiguous bytes per instruction).
// ---------------------------------------------------------------------------
__global__ __launch_bounds__(256) void qkv_proj_kernel(
    const float* __restrict__ x,
    const float* __restrict__ Wq, const float* __restrict__ bq,
    const float* __restrict__ Wk, const float* __restrict__ bk,
    const float* __restrict__ Wv, const float* __restrict__ bv,
    __bf16* __restrict__ Qg, __bf16* __restrict__ Kg, __bf16* __restrict__ Vcg)
{
    __shared__ __bf16 xs[64][40];
    __shared__ __bf16 wt[192][40];

    const int tid  = threadIdx.x;
    const int wid  = tid >> 6;
    const int lane = tid & 63;
    const int l15  = lane & 15;
    const int l4   = lane >> 4;
    const int m0   = blockIdx.x * 64;

    f32x4 acc[4][3];
    #pragma unroll
    for (int i = 0; i < 4; ++i)
        #pragma unroll
        for (int j = 0; j < 3; ++j)
            acc[i][j] = (f32x4){0.f, 0.f, 0.f, 0.f};

    for (int k0 = 0; k0 < 768; k0 += 32) {
        #pragma unroll
        for (int i = 0; i < 2; ++i) {
            int idx = tid + 256 * i;
            int row = idx >> 3;
            int c4  = idx & 7;
            const float4 v = *reinterpret_cast<const float4*>(
                x + (size_t)(m0 + row) * 768 + k0 + c4 * 4);
            bf16x4 t;
            t[0] = (__bf16)v.x; t[1] = (__bf16)v.y;
            t[2] = (__bf16)v.z; t[3] = (__bf16)v.w;
            *reinterpret_cast<bf16x4*>(&xs[row][c4 * 4]) = t;
        }
        #pragma unroll
        for (int i = 0; i < 6; ++i) {
            int idx = tid + 256 * i;
            int kg  = idx / 192;
            int c   = idx - kg * 192;
            const float* Wm = (c < 64) ? Wq : ((c < 128) ? Wk : Wv);
            int cc = c & 63;
            bf16x4 t;
            #pragma unroll
            for (int j = 0; j < 4; ++j)
                t[j] = (__bf16)Wm[(size_t)(k0 + kg * 4 + j) * 64 + cc];
            *reinterpret_cast<bf16x4*>(&wt[c][kg * 4]) = t;
        }
        __syncthreads();

        bf16x8 afrag[4];
        #pragma unroll
        for (int rf = 0; rf < 4; ++rf)
            afrag[rf] = *reinterpret_cast<const bf16x8*>(&xs[rf * 16 + l15][l4 * 8]);
        #pragma unroll
        for (int cf = 0; cf < 3; ++cf) {
            bf16x8 bfrag = *reinterpret_cast<const bf16x8*>(
                &wt[wid * 48 + cf * 16 + l15][l4 * 8]);
            #pragma unroll
            for (int rf = 0; rf < 4; ++rf)
                acc[rf][cf] = MFMA16(afrag[rf], bfrag, acc[rf][cf]);
        }
        __syncthreads();
    }

    #pragma unroll
    for (int cf = 0; cf < 3; ++cf) {
        int col = wid * 48 + cf * 16 + l15;
        int mi  = col >> 6;                   // 0=Q 1=K 2=V
        int h   = col & 63;
        float bias = (mi == 0) ? bq[h] : ((mi == 1) ? bk[h] : bv[h]);
        float scl  = (mi == 0) ? QSCALE : 1.0f;
        #pragma unroll
        for (int rf = 0; rf < 4; ++rf) {
            int r0 = rf * 16 + l4 * 4;
            if (mi == 2) {
                int m  = m0 + r0;
                int bb = m >> 12;
                int n0 = m & 4095;
                int c  = n0 >> 5;                         // key chunk
                int goff = ((l4 ^ (h & 3)) * 8) + (rf & 1) * 4;
                bf16x4 t;
                #pragma unroll
                for (int r = 0; r < 4; ++r)
                    t[r] = (__bf16)(acc[rf][cf][r] + bias);
                *reinterpret_cast<bf16x4*>(
                    Vcg + (((size_t)bb * 128 + c) * 64 + h) * 32 + goff) = t;
            } else {
                __bf16* G = (mi == 0) ? Qg : Kg;
                #pragma unroll
                for (int r = 0; r < 4; ++r)
                    G[(size_t)(m0 + r0 + r) * 64 + h] =
                        (__bf16)((acc[rf][cf][r] + bias) * scl);
            }
        }
    }
}

// ---------------------------------------------------------------------------
// Kernel 2: flash attention — r19 wait structure with SINGLE-buffered V:
// issue_V(t+1) moves AFTER the PV MFMA block (all V_t ds_reads are
// architecturally retired before any consuming MFMA issues, so the DMA
// cannot overwrite unread data; pinned by sched_barrier). vmcnt ledger is
// identical to r19: {K_t,V_t}=8 at top -> W1 vmcnt(4); {V_t,K_{t+1}}=8 at
// W2 -> vmcnt(4); after issue_V: {K_{t+1},V_{t+1}}=8. Tail drains vmcnt(0).
// LDS 12 KB/wave (K dbuf 8 KB + V single 4 KB) = 48 KB/block ->
// 3 blocks/CU = 3 waves/SIMD (+50% TLP vs r19), VGPR unchanged (~92).
// ---------------------------------------------------------------------------
__global__ __launch_bounds__(256, 3) void attn_kernel(
    const __bf16* __restrict__ Qg, const __bf16* __restrict__ Kg,
    const __bf16* __restrict__ Vcg, float* __restrict__ out)
{
    // arena: K 4 waves * 2 bufs * 32*64 bf16 = 32 KB
    //        V 4 waves * 1 buf  * 64*32 bf16 = 16 KB   -> 48 KB
    // epilogue overlay: 256 f32 + [64][68] f32 = 18.4 KB (fits)
    __shared__ __align__(16) char smem[49152];
    __bf16* ksbase = reinterpret_cast<__bf16*>(smem);
    __bf16* vsbase = ksbase + 4 * 2 * 32 * 64;

    const int tid  = threadIdx.x;
    const int wid  = tid >> 6;
    const int lane = tid & 63;
    const int l15  = lane & 15;
    const int l4   = lane >> 4;
    const int ks   = wid;              // private key stream 0..3
    const int b    = blockIdx.x & 7;   // batch -> XCD
    const int qt   = blockIdx.x >> 3;  // 0..63
    const int q0   = qt * 64;

    const __bf16* Kb = Kg  + (size_t)b * 4096 * 64;
    const __bf16* Vb = Vcg + (size_t)b * 128 * 2048;   // [128 chunks][64][32]

    __bf16* kst0 = ksbase + (ks * 2 + 0) * 32 * 64;
    __bf16* kst1 = ksbase + (ks * 2 + 1) * 32 * 64;
    __bf16* vst  = vsbase + ks * 64 * 32;              // single buffer

    // loop-invariant swizzled LDS element offsets (read side)
    int koff[2][2], voff[4];
    #pragma unroll
    for (int dc = 0; dc < 2; ++dc)
        #pragma unroll
        for (int cf = 0; cf < 2; ++cf) {
            int row = cf * 16 + l15;
            koff[dc][cf] = row * 64 + (((dc * 4 + l4) ^ (row & 7)) * 8);
        }
    #pragma unroll
    for (int ht = 0; ht < 4; ++ht) {
        int row = ht * 16 + l15;
        voff[ht] = row * 32 + ((l4 ^ (row & 3)) * 8);
    }

    // staging source addressing: K pre-swizzled; V linear (chunk-major Vc)
    const int krow = lane >> 3;                      // 0..7
    const int kg_s = (lane & 7) ^ (lane >> 3);

    auto issue_K = [&](__bf16* kp, int c) {
        #pragma unroll
        for (int j = 0; j < 4; ++j)
            async_copy16(kp + j * 8 * 64,
                         Kb + (size_t)(c * 32 + j * 8 + krow) * 64 + kg_s * 8);
    };
    auto issue_V = [&](int c) {
        const __bf16* src = Vb + (size_t)c * 2048;   // contiguous 4 KB tile
        #pragma unroll
        for (int j = 0; j < 4; ++j)
            async_copy16(vst + j * 512, src + j * 512 + (lane & 63) * 8);
    };

    // Q B-frags for the four 16-row sets (pre-scaled by QSCALE)
    bf16x8 aq[4][2];
    #pragma unroll
    for (int set = 0; set < 4; ++set)
        #pragma unroll
        for (int dc = 0; dc < 2; ++dc)
            aq[set][dc] = *reinterpret_cast<const bf16x8*>(
                Qg + (size_t)(b * 4096 + q0 + set * 16 + l15) * 64 + dc * 32 + l4 * 8);

    f32x4 lacc[4];
    f32x4 o[4][4];
    #pragma unroll
    for (int set = 0; set < 4; ++set) {
        lacc[set] = (f32x4){0.f, 0.f, 0.f, 0.f};
        #pragma unroll
        for (int ht = 0; ht < 4; ++ht)
            o[set][ht] = (f32x4){0.f, 0.f, 0.f, 0.f};
    }

    const int c0 = ks * 32;            // this wave's first 32-key chunk
    issue_K(kst0, c0);
    issue_V(c0);

    for (int t = 0; t < 32; ++t) {
        const __bf16* kp = (t & 1) ? kst1 : kst0;
        __bf16* kpn = (t & 1) ? kst0 : kst1;
        const bool pre = (t + 1) < 32;

        // W1: K_t ready (V_t still in flight)
        asm volatile("s_waitcnt vmcnt(4)" ::: "memory");
        __builtin_amdgcn_sched_barrier(0);

        bf16x8 kfr[2][2];
        #pragma unroll
        for (int dc = 0; dc < 2; ++dc)
            #pragma unroll
            for (int cf = 0; cf < 2; ++cf)
                kfr[dc][cf] = *reinterpret_cast<const bf16x8*>(kp + koff[dc][cf]);

        if (pre) issue_K(kpn, c0 + t + 1);

        // S^T = K * Q^T
        f32x4 s[4][2];
        #pragma unroll
        for (int set = 0; set < 4; ++set)
            #pragma unroll
            for (int cf = 0; cf < 2; ++cf)
                s[set][cf] = (f32x4){0.f, 0.f, 0.f, 0.f};
        __builtin_amdgcn_s_setprio(1);
        #pragma unroll
        for (int dc = 0; dc < 2; ++dc)
            #pragma unroll
            for (int cf = 0; cf < 2; ++cf)
                #pragma unroll
                for (int set = 0; set < 4; ++set)
                    s[set][cf] = MFMA16(kfr[dc][cf], aq[set][dc], s[set][cf]);
        __builtin_amdgcn_s_setprio(0);

        // p = 2^s; accumulate l as vectors
        #pragma unroll
        for (int set = 0; set < 4; ++set) {
            #pragma unroll
            for (int cf = 0; cf < 2; ++cf)
                #pragma unroll
                for (int r = 0; r < 4; ++r)
                    s[set][cf][r] = fast_exp2(s[set][cf][r]);
            lacc[set] += s[set][0];
            lacc[set] += s[set][1];
        }

        // P^T B-frags (in-lane repack, sigma-permuted key order)
        bf16x8 pb[4];
        #pragma unroll
        for (int set = 0; set < 4; ++set)
            #pragma unroll
            for (int j = 0; j < 4; ++j) {
                pb[set][j]     = (__bf16)s[set][0][j];
                pb[set][j + 4] = (__bf16)s[set][1][j];
            }

        // W2: V_t ready (K_{t+1} in flight); tail drains fully
        if (pre) {
            asm volatile("s_waitcnt vmcnt(4)" ::: "memory");
        } else {
            asm volatile("s_waitcnt vmcnt(0)" ::: "memory");
        }
        __builtin_amdgcn_sched_barrier(0);

        bf16x8 vfr[4];
        #pragma unroll
        for (int ht = 0; ht < 4; ++ht)
            vfr[ht] = *reinterpret_cast<const bf16x8*>(vst + voff[ht]);

        // O^T += V^T * P^T (V_t reads retire before these MFMAs can issue)
        __builtin_amdgcn_s_setprio(1);
        #pragma unroll
        for (int ht = 0; ht < 4; ++ht)
            #pragma unroll
            for (int set = 0; set < 4; ++set)
                o[set][ht] = MFMA16(vfr[ht], pb[set], o[set][ht]);
        __builtin_amdgcn_s_setprio(0);

        // issue V_{t+1} into the SAME buffer — safe: pinned after the PV
        // MFMAs, whose issue required all V_t ds_reads to have retired.
        __builtin_amdgcn_sched_barrier(0);
        if (pre) issue_V(c0 + t + 1);
    }

    // per-wave l partials (q = set*16 + l15)
    float lw[4];
    #pragma unroll
    for (int set = 0; set < 4; ++set) {
        float v = lacc[set][0] + lacc[set][1] + lacc[set][2] + lacc[set][3];
        v += __shfl_xor(v, 16);
        v += __shfl_xor(v, 32);
        lw[set] = v;
    }

    // ---- sequential-overlay merge of the 4 private streams (plain sums) ----
    __syncthreads();
    float* lbuf = reinterpret_cast<float*>(smem);   // [4 ks][64 q]
    float* obuf = lbuf + 256;                       // [64 q][68]
    const int hcol = 4 * l4;

    if (l4 == 0) {
        #pragma unroll
        for (int set = 0; set < 4; ++set)
            lbuf[ks * 64 + set * 16 + l15] = lw[set];
    }
    #pragma unroll
    for (int k = 1; k < 4; ++k) {
        if (ks == k) {
            #pragma unroll
            for (int set = 0; set < 4; ++set)
                #pragma unroll
                for (int ht = 0; ht < 4; ++ht)
                    *reinterpret_cast<f32x4*>(
                        &obuf[(set * 16 + l15) * 68 + ht * 16 + hcol]) = o[set][ht];
        }
        __syncthreads();
        if (ks == 0) {
            #pragma unroll
            for (int set = 0; set < 4; ++set)
                #pragma unroll
                for (int ht = 0; ht < 4; ++ht) {
                    f32x4 p = *reinterpret_cast<const f32x4*>(
                        &obuf[(set * 16 + l15) * 68 + ht * 16 + hcol]);
                    o[set][ht][0] += p[0]; o[set][ht][1] += p[1];
                    o[set][ht][2] += p[2]; o[set][ht][3] += p[3];
                }
        }
        __syncthreads();
    }

    if (ks == 0) {
        #pragma unroll
        for (int set = 0; set < 4; ++set) {
            int q = set * 16 + l15;
            float L = lbuf[q] + lbuf[64 + q] + lbuf[128 + q] + lbuf[192 + q];
            float inv = 1.0f / L;
            #pragma unroll
            for (int ht = 0; ht < 4; ++ht) {
                f32x4 acc = o[set][ht];
                acc[0] *= inv; acc[1] *= inv; acc[2] *= inv; acc[3] *= inv;
                *reinterpret_cast<f32x4*>(
                    out + (size_t)(b * 4096 + q0 + q) * 64 + ht * 16 + hcol) = acc;
            }
        }
    }
}

extern "C" void kernel_launch(void* const* d_in, const int* in_sizes, int n_in,
                              void* d_out, int out_size, void* d_ws, size_t ws_size,
                              hipStream_t stream)
{
    (void)in_sizes; (void)n_in; (void)out_size; (void)ws_size;
    const float* x  = (const float*)d_in[0];
    const float* Wq = (const float*)d_in[1];
    const float* bq = (const float*)d_in[2];
    const float* Wk = (const float*)d_in[3];
    const float* bk = (const float*)d_in[4];
    const float* Wv = (const float*)d_in[5];
    const float* bv = (const float*)d_in[6];
    float* out = (float*)d_out;

    __bf16* Qg  = (__bf16*)d_ws;                    // [32768][64] bf16 (scaled)
    __bf16* Kg  = Qg + (size_t)32768 * 64;          // [32768][64] bf16
    __bf16* Vcg = Kg + (size_t)32768 * 64;          // [8][128][64][32] bf16

    qkv_proj_kernel<<<512, 256, 0, stream>>>(x, Wq, bq, Wk, bk, Wv, bv, Qg, Kg, Vcg);
    attn_kernel<<<512, 256, 0, stream>>>(Qg, Kg, Vcg, out);
}

// Round 24
// 71.521 us; speedup vs baseline: 1.1136x; 1.1136x over previous
//
#include <hip/hip_runtime.h>
#include <stdint.h>
#include <stddef.h>

typedef __bf16 bf16x8 __attribute__((ext_vector_type(8)));
typedef __bf16 bf16x4 __attribute__((ext_vector_type(4)));
typedef float  f32x4  __attribute__((ext_vector_type(4)));

#define MFMA16(A, B, C) __builtin_amdgcn_mfma_f32_16x16x32_bf16((A), (B), (C), 0, 0, 0)

// 0.125 (1/sqrt(64)) * log2(e), folded into Q at projection time.
#define QSCALE 0.18033688011112042f

// Raw v_exp_f32 (2^x); args bounded here so no range guards needed.
#if __has_builtin(__builtin_amdgcn_exp2f)
__device__ __forceinline__ float fast_exp2(float x) {
    return __builtin_amdgcn_exp2f(x);
}
#else
__device__ __forceinline__ float fast_exp2(float x) {
    float r;
    asm("v_exp_f32 %0, %1" : "=v"(r) : "v"(x));
    return r;
}
#endif

// Async global->LDS, 16B per lane. LDS dest is wave-uniform base + lane*16.
__device__ __forceinline__ void async_copy16(__bf16* lds, const __bf16* g) {
    __builtin_amdgcn_global_load_lds(
        (const __attribute__((address_space(1))) void*)g,
        (__attribute__((address_space(3))) void*)lds,
        16, 0, 0);
}

// ---------------------------------------------------------------------------
// Kernel 1: fused QKV projection (best measured config, r19/r22).
//   x [32768][768] fp32 -> Q (pre-scaled by QSCALE), K bf16 row-major
//   [32768][64]; V stored CHUNK-MAJOR: Vc[b][128 chunks][64 h][32 k'] with
//   (a) the sigma key-permutation inside each 32-token chunk:
//       token (16*hi + 4*g + r) -> k' position (8*g + 4*hi + r), and
//   (b) the LDS stage swizzle baked in: the bf16x4 destined for (h, granule
//       gt) is stored at granule gt^(h&3) -> attention DMA is fully linear.
// ---------------------------------------------------------------------------
__global__ __launch_bounds__(256) void qkv_proj_kernel(
    const float* __restrict__ x,
    const float* __restrict__ Wq, const float* __restrict__ bq,
    const float* __restrict__ Wk, const float* __restrict__ bk,
    const float* __restrict__ Wv, const float* __restrict__ bv,
    __bf16* __restrict__ Qg, __bf16* __restrict__ Kg, __bf16* __restrict__ Vcg)
{
    __shared__ __bf16 xs[64][40];
    __shared__ __bf16 wt[192][40];

    const int tid  = threadIdx.x;
    const int wid  = tid >> 6;
    const int lane = tid & 63;
    const int l15  = lane & 15;
    const int l4   = lane >> 4;
    const int m0   = blockIdx.x * 64;

    f32x4 acc[4][3];
    #pragma unroll
    for (int i = 0; i < 4; ++i)
        #pragma unroll
        for (int j = 0; j < 3; ++j)
            acc[i][j] = (f32x4){0.f, 0.f, 0.f, 0.f};

    for (int k0 = 0; k0 < 768; k0 += 32) {
        #pragma unroll
        for (int i = 0; i < 2; ++i) {
            int idx = tid + 256 * i;
            int row = idx >> 3;
            int c4  = idx & 7;
            const float4 v = *reinterpret_cast<const float4*>(
                x + (size_t)(m0 + row) * 768 + k0 + c4 * 4);
            bf16x4 t;
            t[0] = (__bf16)v.x; t[1] = (__bf16)v.y;
            t[2] = (__bf16)v.z; t[3] = (__bf16)v.w;
            *reinterpret_cast<bf16x4*>(&xs[row][c4 * 4]) = t;
        }
        #pragma unroll
        for (int i = 0; i < 6; ++i) {
            int idx = tid + 256 * i;
            int kg  = idx / 192;
            int c   = idx - kg * 192;
            const float* Wm = (c < 64) ? Wq : ((c < 128) ? Wk : Wv);
            int cc = c & 63;
            bf16x4 t;
            #pragma unroll
            for (int j = 0; j < 4; ++j)
                t[j] = (__bf16)Wm[(size_t)(k0 + kg * 4 + j) * 64 + cc];
            *reinterpret_cast<bf16x4*>(&wt[c][kg * 4]) = t;
        }
        __syncthreads();

        bf16x8 afrag[4];
        #pragma unroll
        for (int rf = 0; rf < 4; ++rf)
            afrag[rf] = *reinterpret_cast<const bf16x8*>(&xs[rf * 16 + l15][l4 * 8]);
        #pragma unroll
        for (int cf = 0; cf < 3; ++cf) {
            bf16x8 bfrag = *reinterpret_cast<const bf16x8*>(
                &wt[wid * 48 + cf * 16 + l15][l4 * 8]);
            #pragma unroll
            for (int rf = 0; rf < 4; ++rf)
                acc[rf][cf] = MFMA16(afrag[rf], bfrag, acc[rf][cf]);
        }
        __syncthreads();
    }

    #pragma unroll
    for (int cf = 0; cf < 3; ++cf) {
        int col = wid * 48 + cf * 16 + l15;
        int mi  = col >> 6;                   // 0=Q 1=K 2=V
        int h   = col & 63;
        float bias = (mi == 0) ? bq[h] : ((mi == 1) ? bk[h] : bv[h]);
        float scl  = (mi == 0) ? QSCALE : 1.0f;
        #pragma unroll
        for (int rf = 0; rf < 4; ++rf) {
            int r0 = rf * 16 + l4 * 4;
            if (mi == 2) {
                int m  = m0 + r0;
                int bb = m >> 12;
                int n0 = m & 4095;
                int c  = n0 >> 5;                         // key chunk
                int goff = ((l4 ^ (h & 3)) * 8) + (rf & 1) * 4;
                bf16x4 t;
                #pragma unroll
                for (int r = 0; r < 4; ++r)
                    t[r] = (__bf16)(acc[rf][cf][r] + bias);
                *reinterpret_cast<bf16x4*>(
                    Vcg + (((size_t)bb * 128 + c) * 64 + h) * 32 + goff) = t;
            } else {
                __bf16* G = (mi == 0) ? Qg : Kg;
                #pragma unroll
                for (int r = 0; r < 4; ++r)
                    G[(size_t)(m0 + r0 + r) * 64 + h] =
                        (__bf16)((acc[rf][cf][r] + bias) * scl);
            }
        }
    }
}

// ---------------------------------------------------------------------------
// Kernel 2: flash attention — best measured config (71.3-71.6 us total).
// Barrier-free wave-private loop, split counted-vmcnt K/V waits, chunk-major
// coalesced V staging. Block = 4 waves (256 thr) = 64 q x 4096 keys; wave
// ks owns a private 1024-key stream and private dbuf K[32][64]/V[64][32]
// LDS tiles (16 KB/wave, 64 KB/block -> 2 blocks/CU). No max tracking
// (bounded scores), raw v_exp_f32, sigma-permuted PV, epilogue
// sequential-overlay merge (plain sums, exact).
// ---------------------------------------------------------------------------
__global__ __launch_bounds__(256, 2) void attn_kernel(
    const __bf16* __restrict__ Qg, const __bf16* __restrict__ Kg,
    const __bf16* __restrict__ Vcg, float* __restrict__ out)
{
    __shared__ __align__(16) char smem[65536];
    __bf16* ksbase = reinterpret_cast<__bf16*>(smem);
    __bf16* vsbase = ksbase + 4 * 2 * 32 * 64;

    const int tid  = threadIdx.x;
    const int wid  = tid >> 6;
    const int lane = tid & 63;
    const int l15  = lane & 15;
    const int l4   = lane >> 4;
    const int ks   = wid;              // private key stream 0..3
    const int b    = blockIdx.x & 7;   // batch -> XCD
    const int qt   = blockIdx.x >> 3;  // 0..63
    const int q0   = qt * 64;

    const __bf16* Kb = Kg  + (size_t)b * 4096 * 64;
    const __bf16* Vb = Vcg + (size_t)b * 128 * 2048;   // [128 chunks][64][32]

    __bf16* kst0 = ksbase + (ks * 2 + 0) * 32 * 64;
    __bf16* kst1 = ksbase + (ks * 2 + 1) * 32 * 64;
    __bf16* vst0 = vsbase + (ks * 2 + 0) * 64 * 32;
    __bf16* vst1 = vsbase + (ks * 2 + 1) * 64 * 32;

    // loop-invariant swizzled LDS element offsets (read side)
    int koff[2][2], voff[4];
    #pragma unroll
    for (int dc = 0; dc < 2; ++dc)
        #pragma unroll
        for (int cf = 0; cf < 2; ++cf) {
            int row = cf * 16 + l15;
            koff[dc][cf] = row * 64 + (((dc * 4 + l4) ^ (row & 7)) * 8);
        }
    #pragma unroll
    for (int ht = 0; ht < 4; ++ht) {
        int row = ht * 16 + l15;
        voff[ht] = row * 32 + ((l4 ^ (row & 3)) * 8);
    }

    // staging source addressing: K pre-swizzled; V linear (chunk-major Vc)
    const int krow = lane >> 3;                      // 0..7
    const int kg_s = (lane & 7) ^ (lane >> 3);

    auto issue_K = [&](__bf16* kp, int c) {
        #pragma unroll
        for (int j = 0; j < 4; ++j)
            async_copy16(kp + j * 8 * 64,
                         Kb + (size_t)(c * 32 + j * 8 + krow) * 64 + kg_s * 8);
    };
    auto issue_V = [&](__bf16* vp, int c) {
        const __bf16* src = Vb + (size_t)c * 2048;   // contiguous 4 KB tile
        #pragma unroll
        for (int j = 0; j < 4; ++j)
            async_copy16(vp + j * 512, src + j * 512 + (lane & 63) * 8);
    };

    // Q B-frags for the four 16-row sets (pre-scaled by QSCALE)
    bf16x8 aq[4][2];
    #pragma unroll
    for (int set = 0; set < 4; ++set)
        #pragma unroll
        for (int dc = 0; dc < 2; ++dc)
            aq[set][dc] = *reinterpret_cast<const bf16x8*>(
                Qg + (size_t)(b * 4096 + q0 + set * 16 + l15) * 64 + dc * 32 + l4 * 8);

    f32x4 lacc[4];
    f32x4 o[4][4];
    #pragma unroll
    for (int set = 0; set < 4; ++set) {
        lacc[set] = (f32x4){0.f, 0.f, 0.f, 0.f};
        #pragma unroll
        for (int ht = 0; ht < 4; ++ht)
            o[set][ht] = (f32x4){0.f, 0.f, 0.f, 0.f};
    }

    const int c0 = ks * 32;            // this wave's first 32-key chunk
    issue_K(kst0, c0);
    issue_V(vst0, c0);

    for (int t = 0; t < 32; ++t) {
        const __bf16* kp = (t & 1) ? kst1 : kst0;
        const __bf16* vp = (t & 1) ? vst1 : vst0;
        __bf16* kpn = (t & 1) ? kst0 : kst1;
        __bf16* vpn = (t & 1) ? vst0 : vst1;
        const bool pre = (t + 1) < 32;

        // W1: K_t ready (V_t still in flight)
        asm volatile("s_waitcnt vmcnt(4)" ::: "memory");
        __builtin_amdgcn_sched_barrier(0);

        bf16x8 kfr[2][2];
        #pragma unroll
        for (int dc = 0; dc < 2; ++dc)
            #pragma unroll
            for (int cf = 0; cf < 2; ++cf)
                kfr[dc][cf] = *reinterpret_cast<const bf16x8*>(kp + koff[dc][cf]);

        if (pre) issue_K(kpn, c0 + t + 1);

        // S^T = K * Q^T
        f32x4 s[4][2];
        #pragma unroll
        for (int set = 0; set < 4; ++set)
            #pragma unroll
            for (int cf = 0; cf < 2; ++cf)
                s[set][cf] = (f32x4){0.f, 0.f, 0.f, 0.f};
        __builtin_amdgcn_s_setprio(1);
        #pragma unroll
        for (int dc = 0; dc < 2; ++dc)
            #pragma unroll
            for (int cf = 0; cf < 2; ++cf)
                #pragma unroll
                for (int set = 0; set < 4; ++set)
                    s[set][cf] = MFMA16(kfr[dc][cf], aq[set][dc], s[set][cf]);
        __builtin_amdgcn_s_setprio(0);

        // p = 2^s; accumulate l as vectors
        #pragma unroll
        for (int set = 0; set < 4; ++set) {
            #pragma unroll
            for (int cf = 0; cf < 2; ++cf)
                #pragma unroll
                for (int r = 0; r < 4; ++r)
                    s[set][cf][r] = fast_exp2(s[set][cf][r]);
            lacc[set] += s[set][0];
            lacc[set] += s[set][1];
        }

        // P^T B-frags (in-lane repack, sigma-permuted key order)
        bf16x8 pb[4];
        #pragma unroll
        for (int set = 0; set < 4; ++set)
            #pragma unroll
            for (int j = 0; j < 4; ++j) {
                pb[set][j]     = (__bf16)s[set][0][j];
                pb[set][j + 4] = (__bf16)s[set][1][j];
            }

        // W2: V_t ready (K_{t+1} in flight); tail drains fully
        if (pre) {
            asm volatile("s_waitcnt vmcnt(4)" ::: "memory");
        } else {
            asm volatile("s_waitcnt vmcnt(0)" ::: "memory");
        }
        __builtin_amdgcn_sched_barrier(0);

        bf16x8 vfr[4];
        #pragma unroll
        for (int ht = 0; ht < 4; ++ht)
            vfr[ht] = *reinterpret_cast<const bf16x8*>(vp + voff[ht]);

        if (pre) issue_V(vpn, c0 + t + 1);

        // O^T += V^T * P^T
        __builtin_amdgcn_s_setprio(1);
        #pragma unroll
        for (int ht = 0; ht < 4; ++ht)
            #pragma unroll
            for (int set = 0; set < 4; ++set)
                o[set][ht] = MFMA16(vfr[ht], pb[set], o[set][ht]);
        __builtin_amdgcn_s_setprio(0);
    }

    // per-wave l partials (q = set*16 + l15)
    float lw[4];
    #pragma unroll
    for (int set = 0; set < 4; ++set) {
        float v = lacc[set][0] + lacc[set][1] + lacc[set][2] + lacc[set][3];
        v += __shfl_xor(v, 16);
        v += __shfl_xor(v, 32);
        lw[set] = v;
    }

    // ---- sequential-overlay merge of the 4 private streams (plain sums) ----
    __syncthreads();
    float* lbuf = reinterpret_cast<float*>(smem);   // [4 ks][64 q]
    float* obuf = lbuf + 256;                       // [64 q][68]
    const int hcol = 4 * l4;

    if (l4 == 0) {
        #pragma unroll
        for (int set = 0; set < 4; ++set)
            lbuf[ks * 64 + set * 16 + l15] = lw[set];
    }
    #pragma unroll
    for (int k = 1; k < 4; ++k) {
        if (ks == k) {
            #pragma unroll
            for (int set = 0; set < 4; ++set)
                #pragma unroll
                for (int ht = 0; ht < 4; ++ht)
                    *reinterpret_cast<f32x4*>(
                        &obuf[(set * 16 + l15) * 68 + ht * 16 + hcol]) = o[set][ht];
        }
        __syncthreads();
        if (ks == 0) {
            #pragma unroll
            for (int set = 0; set < 4; ++set)
                #pragma unroll
                for (int ht = 0; ht < 4; ++ht) {
                    f32x4 p = *reinterpret_cast<const f32x4*>(
                        &obuf[(set * 16 + l15) * 68 + ht * 16 + hcol]);
                    o[set][ht][0] += p[0]; o[set][ht][1] += p[1];
                    o[set][ht][2] += p[2]; o[set][ht][3] += p[3];
                }
        }
        __syncthreads();
    }

    if (ks == 0) {
        #pragma unroll
        for (int set = 0; set < 4; ++set) {
            int q = set * 16 + l15;
            float L = lbuf[q] + lbuf[64 + q] + lbuf[128 + q] + lbuf[192 + q];
            float inv = 1.0f / L;
            #pragma unroll
            for (int ht = 0; ht < 4; ++ht) {
                f32x4 acc = o[set][ht];
                acc[0] *= inv; acc[1] *= inv; acc[2] *= inv; acc[3] *= inv;
                *reinterpret_cast<f32x4*>(
                    out + (size_t)(b * 4096 + q0 + q) * 64 + ht * 16 + hcol) = acc;
            }
        }
    }
}

extern "C" void kernel_launch(void* const* d_in, const int* in_sizes, int n_in,
                              void* d_out, int out_size, void* d_ws, size_t ws_size,
                              hipStream_t stream)
{
    (void)in_sizes; (void)n_in; (void)out_size; (void)ws_size;
    const float* x  = (const float*)d_in[0];
    const float* Wq = (const float*)d_in[1];
    const float* bq = (const float*)d_in[2];
    const float* Wk = (const float*)d_in[3];
    const float* bk = (const float*)d_in[4];
    const float* Wv = (const float*)d_in[5];
    const float* bv = (const float*)d_in[6];
    float* out = (float*)d_out;

    __bf16* Qg  = (__bf16*)d_ws;                    // [32768][64] bf16 (scaled)
    __bf16* Kg  = Qg + (size_t)32768 * 64;          // [32768][64] bf16
    __bf16* Vcg = Kg + (size_t)32768 * 64;          // [8][128][64][32] bf16

    qkv_proj_kernel<<<512, 256, 0, stream>>>(x, Wq, bq, Wk, bk, Wv, bv, Qg, Kg, Vcg);
    attn_kernel<<<512, 256, 0, stream>>>(Qg, Kg, Vcg, out);
}